// Round 1
// baseline (592.711 us; speedup 1.0000x reference)
//
#include <hip/hip_runtime.h>

#define EMA_EPS 1e-12f
#define TS 64          // s-rows per block in the fallback scan+norm kernel

// ===== fused single-pass config (requires D == 512) =====
#define FTS   16       // rows per block
#define FD4   128      // float4 per row (D = 512)
#define FREGS 8        // (FTS * FD4) / 256 threads

__device__ __forceinline__ float wave_reduce_sum(float v) {
    #pragma unroll
    for (int off = 32; off > 0; off >>= 1) v += __shfl_xor(v, off, 64);
    return v;
}

// Agent-scope (device) atomics: safe across XCDs (per-XCD L2 not coherent).
__device__ __forceinline__ unsigned ld_acq(const unsigned* p) {
    return __hip_atomic_load(p, __ATOMIC_ACQUIRE, __HIP_MEMORY_SCOPE_AGENT);
}
__device__ __forceinline__ void st_rel(unsigned* p, unsigned v) {
    __hip_atomic_store(p, v, __ATOMIC_RELEASE, __HIP_MEMORY_SCOPE_AGENT);
}
__device__ __forceinline__ float ld_rlx(const float* p) {
    return __hip_atomic_load(p, __ATOMIC_RELAXED, __HIP_MEMORY_SCOPE_AGENT);
}
__device__ __forceinline__ void st_rlx(float* p, float v) {
    __hip_atomic_store(p, v, __ATOMIC_RELAXED, __HIP_MEMORY_SCOPE_AGENT);
}

// ---------------------------------------------------------------------------
// Fused single-pass kernel: load 16 rows of x into registers, compute per-row
// mean/std, weighted within-tile scan, decoupled-lookback for the cross-tile
// prefix (per-batch segmented), then normalize from registers and store.
// x is read exactly once; y written exactly once. Tile order is claimed via an
// atomic ticket so lookback predecessors are guaranteed to have started.
// Partial aggregate is published BEFORE lookback -> no circular wait.
// ---------------------------------------------------------------------------
__global__ __launch_bounds__(256) void ema_fused_kernel(
    const float* __restrict__ x,
    const float* __restrict__ h, const float* __restrict__ alpha_logit,
    const float* __restrict__ gamma, const float* __restrict__ beta,
    float* __restrict__ out,
    unsigned* __restrict__ ctr, unsigned* __restrict__ flags,
    float* __restrict__ aM, float* __restrict__ aS,
    float* __restrict__ iM, float* __restrict__ iS,
    int B, int S)
{
    const int T    = S / FTS;
    const int tid  = threadIdx.x;
    const int lane = tid & 63;
    const int wv   = tid >> 6;
    const int hi   = tid >> 7;          // row parity this thread holds

    __shared__ unsigned sh_tk;
    __shared__ float sh_s[4][FREGS], sh_q[4][FREGS];
    __shared__ float sh_cm[FTS], sh_cs[FTS];   // within-tile inclusive weighted sums
    __shared__ float sh_ex[2];                 // exclusive cross-tile prefix

    if (tid == 0) sh_tk = atomicAdd(ctr, 1u);
    __syncthreads();
    const int tk   = (int)sh_tk;
    const int b    = tk % B;            // interleave batches: 8 chains progress together
    const int jt   = tk / B;            // tile index within batch
    const int s0   = jt * FTS;
    const int rec0 = b * T;
    const int idx  = rec0 + jt;

    const float alpha = 1.0f / (1.0f + __expf(-alpha_logit[0]));
    const float oma   = 1.0f - alpha;
    const float l2a   = __log2f(alpha);

    // ---- load tile into registers (32 VGPR, statically indexed) ----
    const float4* xt = (const float4*)x + ((size_t)(b * S + s0) << 7);
    float4 v[FREGS];
    float ps[FREGS], pq[FREGS];
    #pragma unroll
    for (int it = 0; it < FREGS; ++it) {
        float4 a = xt[it * 256 + tid];
        v[it]  = a;
        ps[it] = a.x + a.y + a.z + a.w;
        pq[it] = a.x*a.x + a.y*a.y + a.z*a.z + a.w*a.w;
    }
    #pragma unroll
    for (int it = 0; it < FREGS; ++it) {
        ps[it] = wave_reduce_sum(ps[it]);
        pq[it] = wave_reduce_sum(pq[it]);
    }
    if (lane == 0) {
        #pragma unroll
        for (int it = 0; it < FREGS; ++it) { sh_s[wv][it] = ps[it]; sh_q[wv][it] = pq[it]; }
    }
    __syncthreads();

    // ---- thread 0: row stats + weighted inclusive scan + publish aggregate ----
    if (tid == 0) {
        float runM = 0.f, runS = 0.f;
        #pragma unroll
        for (int r = 0; r < FTS; ++r) {
            const int p  = r & 1;       // rows 2it+0 live in waves 0,1; 2it+1 in waves 2,3
            const int it = r >> 1;
            float s    = sh_s[2*p][it] + sh_s[2*p+1][it];
            float q    = sh_q[2*p][it] + sh_q[2*p+1][it];
            float mean = s * (1.0f / 512.0f);
            float var  = (q - s * mean) * (1.0f / 511.0f);
            float sd   = sqrtf(fmaxf(var, 0.0f));
            float w    = oma * exp2f((float)(s0 + r) * l2a);
            runM += w * mean;
            runS += w * sd;
            sh_cm[r] = runM;
            sh_cs[r] = runS;
        }
        if (jt == 0) {      // first tile of the batch: inclusive == aggregate
            st_rlx(&iM[idx], runM);
            st_rlx(&iS[idx], runS);
            st_rel(&flags[idx], 2u);
            sh_ex[0] = 0.f; sh_ex[1] = 0.f;
        } else {            // publish partial BEFORE lookback (forward progress)
            st_rlx(&aM[idx], runM);
            st_rlx(&aS[idx], runS);
            st_rel(&flags[idx], 1u);
        }
    }
    __syncthreads();

    // ---- wave 0: windowed decoupled lookback over same-batch predecessors ----
    if (jt > 0 && tid < 64) {
        float exM = 0.f, exS = 0.f;
        int kk = idx - 1;               // lane L inspects record kk - L
        for (;;) {
            const int k = kk - lane;
            const bool valid = (k >= rec0);
            unsigned f = 0;
            if (valid) {
                f = ld_acq(&flags[k]);
                while (f == 0u) { __builtin_amdgcn_s_sleep(1); f = ld_acq(&flags[k]); }
            }
            const unsigned long long fm = __ballot(valid && f == 2u);
            if (fm) {
                // nearest FULL = largest k with flag==2 = smallest lane set
                const int fl = (int)__ffsll((unsigned long long)fm) - 1;
                float vM = 0.f, vS = 0.f;
                if (lane < fl)       { vM = ld_rlx(&aM[k]); vS = ld_rlx(&aS[k]); }
                else if (lane == fl) { vM = ld_rlx(&iM[k]); vS = ld_rlx(&iS[k]); }
                exM += wave_reduce_sum(vM);
                exS += wave_reduce_sum(vS);
                break;
            } else {                    // whole window is partials (rec0 is always FULL,
                float vM = valid ? ld_rlx(&aM[k]) : 0.f;    // so this implies all valid)
                float vS = valid ? ld_rlx(&aS[k]) : 0.f;
                exM += wave_reduce_sum(vM);
                exS += wave_reduce_sum(vS);
                kk -= 64;
            }
        }
        if (lane == 0) {
            sh_ex[0] = exM; sh_ex[1] = exS;
            st_rlx(&iM[idx], exM + sh_cm[FTS-1]);
            st_rlx(&iS[idx], exS + sh_cs[FTS-1]);
            st_rel(&flags[idx], 2u);
        }
    }
    __syncthreads();

    // ---- normalize register-resident tile + store ----
    const float hm = alpha * h[b*2+0] + sh_ex[0];
    const float hs = alpha * h[b*2+1] + sh_ex[1];
    const int c = tid & 127;
    const float4 g  = ((const float4*)gamma)[c];
    const float4 bt = ((const float4*)beta)[c];
    float4* yt = (float4*)out + ((size_t)(b * S + s0) << 7);
    #pragma unroll
    for (int it = 0; it < FREGS; ++it) {
        const int r = 2*it + hi;
        const float m  = hm + sh_cm[r];
        const float rs = 1.0f / fmaxf(hs + sh_cs[r], EMA_EPS);
        const float4 xv = v[it];
        float4 yv;
        yv.x = (xv.x - m) * rs * g.x + bt.x;
        yv.y = (xv.y - m) * rs * g.y + bt.y;
        yv.z = (xv.z - m) * rs * g.z + bt.z;
        yv.w = (xv.w - m) * rs * g.w + bt.w;
        yt[it * 256 + tid] = yv;
    }
    if (jt == T - 1 && tid == 0) {
        float* h_new = out + (size_t)B * S * 512;
        h_new[b*2+0] = hm + sh_cm[FTS-1];
        h_new[b*2+1] = fmaxf(hs + sh_cs[FTS-1], EMA_EPS);
    }
}

// ---------------------------------------------------------------------------
// Fallback path (previous 2-kernel version) for unexpected shapes.
// ---------------------------------------------------------------------------
__global__ __launch_bounds__(256) void ema_stats_kernel(
    const float* __restrict__ x,
    float* __restrict__ mu, float* __restrict__ sigma,
    int nrows, int d4)
{
    int row  = (int)((blockIdx.x * blockDim.x + threadIdx.x) >> 6);
    int lane = threadIdx.x & 63;
    if (row >= nrows) return;

    const float4* xr = (const float4*)(x + (size_t)row * (size_t)(d4 * 4));
    float s = 0.f, sq = 0.f;
    for (int c = lane; c < d4; c += 64) {
        float4 a = xr[c];
        s  += a.x + a.y + a.z + a.w;
        sq += a.x*a.x + a.y*a.y + a.z*a.z + a.w*a.w;
    }
    s  = wave_reduce_sum(s);
    sq = wave_reduce_sum(sq);
    if (lane == 0) {
        int   n    = d4 * 4;
        float mean = s / (float)n;
        float var  = (sq - s * mean) / (float)(n - 1);
        mu[row]    = mean;
        sigma[row] = sqrtf(fmaxf(var, 0.0f));
    }
}

__global__ __launch_bounds__(256) void ema_scan_norm_kernel(
    const float* __restrict__ x,
    const float* __restrict__ mu, const float* __restrict__ sigma,
    const float* __restrict__ h, const float* __restrict__ alpha_logit,
    const float* __restrict__ gamma, const float* __restrict__ beta,
    float* __restrict__ out, int B, int S, int d4_shift)
{
    const int tiles = S / TS;
    const int b     = (int)blockIdx.x / tiles;
    const int tile  = (int)blockIdx.x % tiles;
    const int s0    = tile * TS;
    const int tid   = threadIdx.x;
    const int d4    = 1 << d4_shift;
    const int D     = d4 << 2;

    const float alpha = 1.0f / (1.0f + __expf(-alpha_logit[0]));
    const float oma   = 1.0f - alpha;
    const float l2a   = __log2f(alpha);

    const float* mub = mu    + (size_t)b * S;
    const float* sgb = sigma + (size_t)b * S;

    __shared__ float sh_wm[4], sh_ws[4];
    __shared__ float sh_pm, sh_ps;
    __shared__ float sh_m[TS], sh_r[TS];

    float lm = 0.f, ls = 0.f;
    for (int t = tid; t < s0; t += 256) {
        float w = oma * exp2f((float)t * l2a);
        lm += w * mub[t];
        ls += w * sgb[t];
    }
    lm = wave_reduce_sum(lm);
    ls = wave_reduce_sum(ls);
    if ((tid & 63) == 0) { sh_wm[tid >> 6] = lm; sh_ws[tid >> 6] = ls; }
    __syncthreads();
    if (tid == 0) {
        sh_pm = sh_wm[0] + sh_wm[1] + sh_wm[2] + sh_wm[3];
        sh_ps = sh_ws[0] + sh_ws[1] + sh_ws[2] + sh_ws[3];
    }
    __syncthreads();

    if (tid < 64) {
        const int lane = tid;
        float w  = oma * exp2f((float)(s0 + lane) * l2a);
        float vm = w * mub[s0 + lane];
        float vs = w * sgb[s0 + lane];
        #pragma unroll
        for (int off = 1; off < 64; off <<= 1) {
            float tm = __shfl_up(vm, off, 64);
            float tv = __shfl_up(vs, off, 64);
            if (lane >= off) { vm += tm; vs += tv; }
        }
        float run_m = alpha * h[b * 2 + 0] + sh_pm + vm;
        float run_s = fmaxf(alpha * h[b * 2 + 1] + sh_ps + vs, EMA_EPS);
        sh_m[lane] = run_m;
        sh_r[lane] = 1.0f / run_s;
        if (s0 + TS == S && lane == 63) {
            float* h_new = out + (size_t)B * S * D;
            h_new[b * 2 + 0] = run_m;
            h_new[b * 2 + 1] = run_s;
        }
    }
    __syncthreads();

    const size_t base = (size_t)(b * S + s0) << d4_shift;
    const float4* xb = (const float4*)x + base;
    float4*       yb = (float4*)out + base;
    const float4* g4 = (const float4*)gamma;
    const float4* b4 = (const float4*)beta;
    const int n4 = TS << d4_shift;
    for (int i = tid; i < n4; i += 256) {
        int r = i >> d4_shift;
        int c = i & (d4 - 1);
        float m  = sh_m[r];
        float rs = sh_r[r];
        float4 g  = g4[c];
        float4 bt = b4[c];
        float4 xv = xb[i];
        float4 yv;
        yv.x = (xv.x - m) * rs * g.x + bt.x;
        yv.y = (xv.y - m) * rs * g.y + bt.y;
        yv.z = (xv.z - m) * rs * g.z + bt.z;
        yv.w = (xv.w - m) * rs * g.w + bt.w;
        yb[i] = yv;
    }
}

extern "C" void kernel_launch(void* const* d_in, const int* in_sizes, int n_in,
                              void* d_out, int out_size, void* d_ws, size_t ws_size,
                              hipStream_t stream) {
    const float* x           = (const float*)d_in[0];
    const float* h           = (const float*)d_in[1];
    const float* gamma       = (const float*)d_in[2];
    const float* beta        = (const float*)d_in[3];
    const float* alpha_logit = (const float*)d_in[4];
    float* out = (float*)d_out;

    const int D     = in_sizes[2];          // 512
    const int B     = in_sizes[1] / 2;      // 8
    const int total = in_sizes[0];          // B*S*D
    const int S     = total / (B * D);      // 8192
    const int nrows = B * S;

    if (D == 512 && (S % FTS) == 0) {
        // --- single-pass fused path ---
        const int T  = S / FTS;
        const int NT = B * T;               // 4096 tiles/records
        unsigned* ctr   = (unsigned*)d_ws;
        unsigned* flags = ctr + 64;         // 64-word pad keeps arrays apart
        float* aM = (float*)(flags + NT);
        float* aS = aM + NT;
        float* iM = aS + NT;
        float* iS = iM + NT;
        // clear ticket + flags (16.4 KB); graph-capturable memset node
        hipMemsetAsync(d_ws, 0, (size_t)(64 + NT) * sizeof(unsigned), stream);
        ema_fused_kernel<<<NT, 256, 0, stream>>>(
            x, h, alpha_logit, gamma, beta, out,
            ctr, flags, aM, aS, iM, iS, B, S);
    } else {
        // --- fallback: previous two-kernel path ---
        const int d4 = D / 4;
        const int d4_shift = __builtin_ctz(d4);
        float* mu_ws = (float*)d_ws;
        float* sg_ws = mu_ws + nrows;
        ema_stats_kernel<<<(nrows + 3) / 4, 256, 0, stream>>>(x, mu_ws, sg_ws, nrows, d4);
        ema_scan_norm_kernel<<<B * (S / TS), 256, 0, stream>>>(
            x, mu_ws, sg_ws, h, alpha_logit, gamma, beta, out, B, S, d4_shift);
    }
}

// Round 2
// 279.642 us; speedup vs baseline: 2.1195x; 2.1195x over previous
//
#include <hip/hip_runtime.h>

#define EMA_EPS 1e-12f

typedef float v4f __attribute__((ext_vector_type(4)));

__device__ __forceinline__ float wave_reduce_sum(float v) {
    #pragma unroll
    for (int off = 32; off > 0; off >>= 1) v += __shfl_xor(v, off, 64);
    return v;
}

// ---------------------------------------------------------------------------
// K1: per-row mean/std (ddof=1), premultiplied by the analytic EMA weight
//     w_t = (1-alpha) * alpha^t  (t = row index within the batch).
// One 64-lane wave per row of D floats; grid-stride over rows.
// Output: wm[row] = w_t * mean(row), wsg[row] = w_t * std(row).
// ---------------------------------------------------------------------------
__global__ __launch_bounds__(256) void ema_stats_kernel(
    const float* __restrict__ x,
    float* __restrict__ wm, float* __restrict__ wsg,
    const float* __restrict__ alpha_logit,
    int nrows, int S, int d4)
{
    const float alpha = 1.0f / (1.0f + __expf(-alpha_logit[0]));
    const float oma   = 1.0f - alpha;
    const float l2a   = __log2f(alpha);

    const int lane = threadIdx.x & 63;
    const int gw   = (int)((blockIdx.x * blockDim.x + threadIdx.x) >> 6);
    const int nw   = (int)((gridDim.x * blockDim.x) >> 6);
    const int n    = d4 * 4;

    for (int row = gw; row < nrows; row += nw) {
        const float4* xr = (const float4*)x + (size_t)row * d4;
        float s = 0.f, sq = 0.f;
        for (int c = lane; c < d4; c += 64) {
            float4 a = xr[c];
            s  += a.x + a.y + a.z + a.w;
            sq += a.x*a.x + a.y*a.y + a.z*a.z + a.w*a.w;
        }
        s  = wave_reduce_sum(s);
        sq = wave_reduce_sum(sq);
        if (lane == 0) {
            float mean = s / (float)n;
            float var  = (sq - s * mean) / (float)(n - 1);
            float sd   = sqrtf(fmaxf(var, 0.0f));
            int   t    = row % S;
            float w    = oma * exp2f((float)t * l2a);
            wm[row]  = w * mean;
            wsg[row] = w * sd;
        }
    }
}

// ---------------------------------------------------------------------------
// K_scan: exact inclusive prefix sum of the weighted stats, one block per
// batch (256 threads, chunked block-scan). Produces per-row mu_cum and
// 1/max(sigma_cum, EPS), plus h_new. 65536 elements total -> a few us.
// ---------------------------------------------------------------------------
__global__ __launch_bounds__(256) void ema_scan_kernel(
    const float* __restrict__ wm, const float* __restrict__ wsg,
    const float* __restrict__ h, const float* __restrict__ alpha_logit,
    float* __restrict__ muc, float* __restrict__ rsc,
    float* __restrict__ h_new, int S)
{
    const int b    = (int)blockIdx.x;
    const int tid  = (int)threadIdx.x;
    const int lane = tid & 63;
    const int wv   = tid >> 6;

    const float alpha = 1.0f / (1.0f + __expf(-alpha_logit[0]));

    __shared__ float pm[4], psg[4];

    float cm = alpha * h[2 * b + 0];
    float cs = alpha * h[2 * b + 1];
    const size_t o = (size_t)b * S;

    for (int base = 0; base < S; base += 256) {
        const int i = base + tid;
        float vm = 0.f, vs = 0.f;
        if (i < S) { vm = wm[o + i]; vs = wsg[o + i]; }

        // wave-level inclusive scan
        #pragma unroll
        for (int off = 1; off < 64; off <<= 1) {
            float tm = __shfl_up(vm, off, 64);
            float tv = __shfl_up(vs, off, 64);
            if (lane >= off) { vm += tm; vs += tv; }
        }
        if (lane == 63) { pm[wv] = vm; psg[wv] = vs; }
        __syncthreads();

        // add carry + lower-wave offsets (wv is wave-uniform -> no divergence)
        float om = cm, os = cs;
        #pragma unroll
        for (int w2 = 0; w2 < 3; ++w2) {
            if (w2 < wv) { om += pm[w2]; os += psg[w2]; }
        }
        const float m  = om + vm;
        const float sg = os + vs;
        if (i < S) {
            muc[o + i] = m;
            rsc[o + i] = 1.0f / fmaxf(sg, EMA_EPS);
        }
        if (i == S - 1) {
            h_new[2 * b + 0] = m;
            h_new[2 * b + 1] = fmaxf(sg, EMA_EPS);
        }
        __syncthreads();
        cm += pm[0] + pm[1] + pm[2] + pm[3];
        cs += psg[0] + psg[1] + psg[2] + psg[3];
        __syncthreads();   // pm/psg reused next chunk
    }
}

// ---------------------------------------------------------------------------
// K2: pure streaming normalize. One wave per row, grid-stride. x is L3-warm
// from K1; mu/rs are broadcast loads; y is written with non-temporal stores
// so the output stream does not evict x from L3.
// ---------------------------------------------------------------------------
__global__ __launch_bounds__(256) void ema_norm_kernel(
    const float* __restrict__ x,
    const float* __restrict__ muc, const float* __restrict__ rsc,
    const float* __restrict__ gamma, const float* __restrict__ beta,
    float* __restrict__ out, int nrows, int d4)
{
    const int lane = threadIdx.x & 63;
    const int gw   = (int)((blockIdx.x * blockDim.x + threadIdx.x) >> 6);
    const int nw   = (int)((gridDim.x * blockDim.x) >> 6);

    const float4* g4 = (const float4*)gamma;
    const float4* b4 = (const float4*)beta;

    for (int row = gw; row < nrows; row += nw) {
        const float m  = muc[row];
        const float rs = rsc[row];
        const float4* xr = (const float4*)x + (size_t)row * d4;
        v4f*          yr = (v4f*)out + (size_t)row * d4;
        for (int c = lane; c < d4; c += 64) {
            float4 xv = xr[c];
            float4 g  = g4[c];
            float4 bt = b4[c];
            v4f yv;
            yv.x = (xv.x - m) * rs * g.x + bt.x;
            yv.y = (xv.y - m) * rs * g.y + bt.y;
            yv.z = (xv.z - m) * rs * g.z + bt.z;
            yv.w = (xv.w - m) * rs * g.w + bt.w;
            __builtin_nontemporal_store(yv, &yr[c]);
        }
    }
}

extern "C" void kernel_launch(void* const* d_in, const int* in_sizes, int n_in,
                              void* d_out, int out_size, void* d_ws, size_t ws_size,
                              hipStream_t stream) {
    const float* x           = (const float*)d_in[0];
    const float* h           = (const float*)d_in[1];
    const float* gamma       = (const float*)d_in[2];
    const float* beta        = (const float*)d_in[3];
    const float* alpha_logit = (const float*)d_in[4];
    float* out = (float*)d_out;

    const int D     = in_sizes[2];          // 512
    const int B     = in_sizes[1] / 2;      // 8
    const int total = in_sizes[0];          // B*S*D
    const int S     = total / (B * D);      // 8192
    const int nrows = B * S;
    const int d4    = D / 4;

    float* wm  = (float*)d_ws;
    float* wsg = wm  + nrows;
    float* muc = wsg + nrows;
    float* rsc = muc + nrows;
    float* h_new = out + (size_t)total;

    // K1: weighted per-row stats (reads x once from HBM, leaves it in L3)
    ema_stats_kernel<<<2048, 256, 0, stream>>>(x, wm, wsg, alpha_logit, nrows, S, d4);

    // K_scan: exact per-batch prefix (tiny)
    ema_scan_kernel<<<B, 256, 0, stream>>>(wm, wsg, h, alpha_logit, muc, rsc, h_new, S);

    // K2: barrier-free streaming normalize (x from L3, nt stores for y)
    ema_norm_kernel<<<2048, 256, 0, stream>>>(x, muc, rsc, gamma, beta, out, nrows, d4);
}